// Round 5
// baseline (301.627 us; speedup 1.0000x reference)
//
#include <hip/hip_runtime.h>
#include <cstdint>

typedef short  short8  __attribute__((ext_vector_type(8)));
typedef ushort ushort8 __attribute__((ext_vector_type(8)));
typedef float  f32x4   __attribute__((ext_vector_type(4)));

#define BATCH 4
#define CIN   256
#define COUT  256
#define HH    96
#define WW    96
#define HWSZ  9216
#define GN_G  16
#define EPSV  1e-5f
#define BN    16            // positions per block
#define NPB   576           // position-blocks per batch (9216/16)
#define NWG   (BATCH*NPB)   // 2304 blocks, %8==0 -> bijective XCD swizzle

__device__ __forceinline__ float bf2f(ushort u) {
    return __uint_as_float(((uint32_t)u) << 16);
}
__device__ __forceinline__ ushort f2bf(float f) {
    uint32_t u = __float_as_uint(f);
    u += 0x7FFFu + ((u >> 16) & 1u);   // round-to-nearest-even
    return (ushort)(u >> 16);
}

// ---- x: [b][c][p] fp32 -> xn: [b][p][c] bf16 (tiled transpose via LDS)
__global__ __launch_bounds__(256)
void nhwc_kernel(const float* __restrict__ x, ushort* __restrict__ xn) {
    __shared__ ushort tile[64][66];
    const int b  = blockIdx.z;
    const int cb = blockIdx.y * 64;
    const int pb = blockIdx.x * 64;
    const int t  = threadIdx.x;
    {
        const int pl = t & 63;
        const int cq = t >> 6;
        #pragma unroll
        for (int i = 0; i < 16; ++i) {
            const int c = cq * 16 + i;
            tile[c][pl] = f2bf(x[((size_t)b * CIN + cb + c) * HWSZ + pb + pl]);
        }
    }
    __syncthreads();
    {
        const int cl = t & 63;
        const int pq = t >> 6;
        #pragma unroll
        for (int i = 0; i < 16; ++i) {
            const int p = pq * 16 + i;
            xn[((size_t)b * HWSZ + pb + p) * CIN + cb + cl] = tile[cl][p];
        }
    }
}

// ---- weight [cout][cin][3][3] fp32 -> Wp[kb8][cout][8] bf16, globalK = tap*256 + cin
__global__ __launch_bounds__(256)
void repack_w_kernel(const float* __restrict__ w, ushort* __restrict__ wp) {
    const int d    = blockIdx.x * 256 + threadIdx.x;
    const int j    = d & 7;
    const int cout = (d >> 3) & 255;
    const int kb8  = d >> 11;
    const int ktap = kb8 >> 5;
    const int cin  = ((kb8 & 31) << 3) | j;
    wp[d] = f2bf(w[cout * (CIN * 9) + cin * 9 + ktap]);
}

// ---- fused deformable-conv GEMM + GN partial stats
__global__ __launch_bounds__(256, 8)
void dcn_mfma_kernel(const ushort* __restrict__ xn, const float* __restrict__ off,
                     const float* __restrict__ msk, const ushort* __restrict__ wp,
                     float* __restrict__ out, float* __restrict__ part) {
    __shared__ ushort buf[2][BN * 128];   // 2 x 4 KB, swizzled 256B rows

    const int bid  = blockIdx.x;
    const int swz  = (bid & 7) * (NWG / 8) + (bid >> 3);   // XCD-contiguous chunks
    const int b    = swz / NPB;
    const int pblk = swz - b * NPB;
    const int p0   = pblk * BN;

    const int t    = threadIdx.x;
    const int lane = t & 63;
    const int wid  = t >> 6;

    // staging role: position pl (0..15), channel 8-slice sub (0..15)
    const int pl  = t & 15;
    const int sub = t >> 4;
    const int pos = p0 + pl;
    const int hh  = pos / WW;
    const int ww  = pos - hh * WW;

    int   sidx[4];
    float swgt[4];

    auto coords = [&](int k) {
        const size_t obase = ((size_t)b * 18 + 2 * k) * HWSZ + pos;
        const float oy = off[obase];
        const float ox = off[obase + HWSZ];
        const float m  = msk[((size_t)b * 9 + k) * HWSZ + pos];
        const float py = (float)(hh + k / 3 - 1) + oy;
        const float px = (float)(ww + k % 3 - 1) + ox;
        const float y0 = floorf(py), x0 = floorf(px);
        #pragma unroll
        for (int dy = 0; dy < 2; ++dy)
            #pragma unroll
            for (int dx = 0; dx < 2; ++dx) {
                const float yy = y0 + (float)dy, xx = x0 + (float)dx;
                const float wb = (1.f - fabsf(py - yy)) * (1.f - fabsf(px - xx));
                const bool valid = (yy >= 0.f) && (yy < (float)HH) && (xx >= 0.f) && (xx < (float)WW);
                int yi = (int)yy; yi = yi < 0 ? 0 : (yi > HH - 1 ? HH - 1 : yi);
                int xi = (int)xx; xi = xi < 0 ? 0 : (xi > WW - 1 ? WW - 1 : xi);
                sidx[dy * 2 + dx] = yi * WW + xi;
                swgt[dy * 2 + dx] = valid ? wb * m : 0.f;
            }
    };

    // stage one 128-channel half-tap: row=pos (256B), col byte ^= (row&15)<<4
    auto stage = [&](int half, ushort* dst) {
        const ushort* xb = xn + (size_t)b * HWSZ * CIN + half * 128 + sub * 8;
        char* drow = (char*)dst + pl * 256;
        const int sw = pl << 4;
        const ushort8 v0 = *(const ushort8*)(xb + (size_t)sidx[0] * CIN);
        const ushort8 v1 = *(const ushort8*)(xb + (size_t)sidx[1] * CIN);
        const ushort8 v2 = *(const ushort8*)(xb + (size_t)sidx[2] * CIN);
        const ushort8 v3 = *(const ushort8*)(xb + (size_t)sidx[3] * CIN);
        ushort8 o;
        #pragma unroll
        for (int j = 0; j < 8; ++j)
            o[j] = f2bf(swgt[0] * bf2f(v0[j]) + swgt[1] * bf2f(v1[j])
                      + swgt[2] * bf2f(v2[j]) + swgt[3] * bf2f(v3[j]));
        *(ushort8*)(drow + ((sub * 16) ^ sw)) = o;
    };

    f32x4 acc[4];
    #pragma unroll
    for (int i = 0; i < 4; ++i)
        acc[i] = (f32x4){0.f, 0.f, 0.f, 0.f};

    const int arow = lane & 15;
    const int akb  = lane >> 4;
    const int asw  = arow << 4;

    auto mfma_chunk = [&](int kb8base, const ushort* src) {
        const char* srow = (const char*)src;
        #pragma unroll
        for (int ks = 0; ks < 4; ++ks) {
            short8 af[4];
            const ushort* wrow = wp + ((size_t)(kb8base + ks * 4 + akb) * COUT + wid * 64 + arow) * 8;
            #pragma unroll
            for (int mt = 0; mt < 4; ++mt)
                af[mt] = *(const short8*)(wrow + mt * 16 * 8);
            const int cb = (ks * 64 + akb * 16) ^ asw;
            const short8 bfr = *(const short8*)(srow + arow * 256 + cb);
            #pragma unroll
            for (int mt = 0; mt < 4; ++mt)
                acc[mt] = __builtin_amdgcn_mfma_f32_16x16x32_bf16(
                    af[mt], bfr, acc[mt], 0, 0, 0);
        }
    };

    coords(0);
    stage(0, buf[0]);
    __syncthreads();
    int cur = 0;
    #pragma unroll 2
    for (int c = 0; c < 18; ++c) {
        if (c < 17) {
            const int nc = c + 1;
            if (!(nc & 1)) coords(nc >> 1);
            stage(nc & 1, buf[cur ^ 1]);      // issue next-chunk gathers before MFMA
        }
        mfma_chunk(c * 16, buf[cur]);
        __syncthreads();
        cur ^= 1;
    }

    // ---- epilogue: C/D layout col=lane&15 (pos), row=(lane>>4)*4+r (cout)
    const int prow = lane & 15;
    const int crow = (lane >> 4) * 4;
    #pragma unroll
    for (int mt = 0; mt < 4; ++mt) {
        const int cout = wid * 64 + mt * 16 + crow;
        const int opos = p0 + prow;
        float* op = out + ((size_t)b * COUT + cout) * HWSZ + opos;
        #pragma unroll
        for (int r = 0; r < 4; ++r)
            op[(size_t)r * HWSZ] = acc[mt][r];
    }

    // ---- GN partial stats: wave wid's mt-subtile is exactly group wid*4+mt
    #pragma unroll
    for (int mt = 0; mt < 4; ++mt) {
        float s = 0.f, q = 0.f;
        #pragma unroll
        for (int r = 0; r < 4; ++r) {
            const float v = acc[mt][r];
            s += v; q += v * v;
        }
        #pragma unroll
        for (int o = 32; o > 0; o >>= 1) {
            s += __shfl_xor(s, o);
            q += __shfl_xor(q, o);
        }
        if (lane == 0) {
            const int bg = b * GN_G + wid * 4 + mt;
            part[((size_t)bg * NPB + pblk) * 2]     = s;
            part[((size_t)bg * NPB + pblk) * 2 + 1] = q;
        }
    }
}

// ---- reduce partials -> stats[bg] = {mean, var}; 256 threads, 4 per bg
__global__ void gn_final_kernel(const float* __restrict__ part, float* __restrict__ stats) {
    const int t  = threadIdx.x;
    const int bg = t >> 2;
    const int j  = t & 3;
    float s = 0.f, q = 0.f;
    for (int i = j; i < NPB; i += 4) {
        s += part[((size_t)bg * NPB + i) * 2];
        q += part[((size_t)bg * NPB + i) * 2 + 1];
    }
    s += __shfl_xor(s, 1); q += __shfl_xor(q, 1);
    s += __shfl_xor(s, 2); q += __shfl_xor(q, 2);
    if (j == 0) {
        const float invn = 1.f / (float)((COUT / GN_G) * HWSZ);
        const float mean = s * invn;
        stats[bg * 2]     = mean;
        stats[bg * 2 + 1] = q * invn - mean * mean;
    }
}

// ---- GroupNorm apply (in place)
__global__ __launch_bounds__(256)
void gn_apply_kernel(float* __restrict__ y, const float* __restrict__ stats,
                     const float* __restrict__ gamma, const float* __restrict__ beta) {
    const int i = blockIdx.x * 256 + threadIdx.x;       // float4 index
    const int e = i * 4;
    const int c  = (e / HWSZ) & (COUT - 1);
    const int bg = e / (HWSZ * (COUT / GN_G));
    const float mean = stats[bg * 2];
    const float var  = stats[bg * 2 + 1];
    const float inv  = rsqrtf(var + EPSV);
    const float sc = inv * gamma[c];
    const float sh = beta[c] - mean * sc;
    float4 v = ((float4*)y)[i];
    v.x = v.x * sc + sh;
    v.y = v.y * sc + sh;
    v.z = v.z * sc + sh;
    v.w = v.w * sc + sh;
    ((float4*)y)[i] = v;
}

extern "C" void kernel_launch(void* const* d_in, const int* in_sizes, int n_in,
                              void* d_out, int out_size, void* d_ws, size_t ws_size,
                              hipStream_t stream) {
    const float* x      = (const float*)d_in[0];
    const float* offset = (const float*)d_in[1];
    const float* mask   = (const float*)d_in[2];
    const float* weight = (const float*)d_in[3];
    const float* gamma  = (const float*)d_in[4];
    const float* beta   = (const float*)d_in[5];
    float* out = (float*)d_out;

    // ws: xn bf16 (18.9 MB) | wp bf16 (1.18 MB) | part (295 KB) | stats (512 B)
    ushort* xn    = (ushort*)d_ws;
    ushort* wp    = xn + (size_t)BATCH * HWSZ * CIN;
    float*  part  = (float*)(wp + (size_t)9 * CIN * COUT);
    float*  stats = part + (size_t)BATCH * GN_G * NPB * 2;

    {
        dim3 g(HWSZ / 64, CIN / 64, BATCH);
        nhwc_kernel<<<g, 256, 0, stream>>>(x, xn);
    }
    repack_w_kernel<<<9 * CIN * COUT / 256, 256, 0, stream>>>(weight, wp);

    dcn_mfma_kernel<<<NWG, 256, 0, stream>>>(xn, offset, mask, wp, out, part);

    gn_final_kernel<<<1, 256, 0, stream>>>(part, stats);
    gn_apply_kernel<<<(size_t)BATCH * COUT * HWSZ / 4 / 256, 256, 0, stream>>>(out, stats, gamma, beta);
}

// Round 6
// 198.961 us; speedup vs baseline: 1.5160x; 1.5160x over previous
//
#include <hip/hip_runtime.h>
#include <cstdint>

typedef short  short8  __attribute__((ext_vector_type(8)));
typedef ushort ushort8 __attribute__((ext_vector_type(8)));
typedef float  f32x4   __attribute__((ext_vector_type(4)));

#define BATCH 4
#define CIN   256
#define COUT  256
#define HH    96
#define WW    96
#define HWSZ  9216
#define GN_G  16
#define EPSV  1e-5f
#define BN    64            // positions per block
#define NPB   144           // position-blocks per batch (9216/64)
#define NWG   (BATCH*NPB)   // 576 blocks, %8==0 -> bijective XCD swizzle

__device__ __forceinline__ float bf2f(ushort u) {
    return __uint_as_float(((uint32_t)u) << 16);
}
__device__ __forceinline__ ushort f2bf(float f) {
    uint32_t u = __float_as_uint(f);
    u += 0x7FFFu + ((u >> 16) & 1u);   // round-to-nearest-even
    return (ushort)(u >> 16);
}

// ---- x: [b][c][p] fp32 -> xn: [b][p][c] bf16 (tiled transpose via LDS)
__global__ __launch_bounds__(256)
void nhwc_kernel(const float* __restrict__ x, ushort* __restrict__ xn) {
    __shared__ ushort tile[64][66];
    const int b  = blockIdx.z;
    const int cb = blockIdx.y * 64;
    const int pb = blockIdx.x * 64;
    const int t  = threadIdx.x;
    {
        const int pl = t & 63;
        const int cq = t >> 6;
        #pragma unroll
        for (int i = 0; i < 16; ++i) {
            const int c = cq * 16 + i;
            tile[c][pl] = f2bf(x[((size_t)b * CIN + cb + c) * HWSZ + pb + pl]);
        }
    }
    __syncthreads();
    {
        const int cl = t & 63;
        const int pq = t >> 6;
        #pragma unroll
        for (int i = 0; i < 16; ++i) {
            const int p = pq * 16 + i;
            xn[((size_t)b * HWSZ + pb + p) * CIN + cb + cl] = tile[cl][p];
        }
    }
}

// ---- weight [cout][cin][3][3] fp32 -> Wp[kb8][cout][8] bf16, globalK = tap*256 + cin
__global__ __launch_bounds__(256)
void repack_w_kernel(const float* __restrict__ w, ushort* __restrict__ wp) {
    const int d    = blockIdx.x * 256 + threadIdx.x;
    const int j    = d & 7;
    const int cout = (d >> 3) & 255;
    const int kb8  = d >> 11;
    const int ktap = kb8 >> 5;
    const int cin  = ((kb8 & 31) << 3) | j;
    wp[d] = f2bf(w[cout * (CIN * 9) + cin * 9 + ktap]);
}

// ---- fused deformable-conv GEMM + GN partial stats (T14 async-stage split)
__global__ __launch_bounds__(256, 3)
void dcn_mfma_kernel(const ushort* __restrict__ xn, const float* __restrict__ off,
                     const float* __restrict__ msk, const ushort* __restrict__ wp,
                     float* __restrict__ out, float* __restrict__ part) {
    __shared__ ushort buf[2][BN * 128];   // 2 x 16 KB, swizzled 256B rows

    const int bid  = blockIdx.x;
    const int swz  = (bid & 7) * (NWG / 8) + (bid >> 3);   // XCD-contiguous chunks
    const int b    = swz / NPB;
    const int pblk = swz - b * NPB;
    const int p0   = pblk * BN;

    const int t    = threadIdx.x;
    const int lane = t & 63;
    const int wid  = t >> 6;

    // staging role: row (position) pl, channel quarter sub (32 ch)
    const int pl  = (t & 15) | (wid << 4);
    const int sub = (t >> 4) & 3;
    const int pos = p0 + pl;
    const int hh  = pos / WW;
    const int ww  = pos - hh * WW;

    int   idxc[4];
    float wgtc[4];

    auto coords = [&](int k) {
        const size_t obase = ((size_t)b * 18 + 2 * k) * HWSZ + pos;
        const float oy = off[obase];
        const float ox = off[obase + HWSZ];
        const float m  = msk[((size_t)b * 9 + k) * HWSZ + pos];
        const float py = (float)(hh + k / 3 - 1) + oy;
        const float px = (float)(ww + k % 3 - 1) + ox;
        const float y0 = floorf(py), x0 = floorf(px);
        #pragma unroll
        for (int dy = 0; dy < 2; ++dy)
            #pragma unroll
            for (int dx = 0; dx < 2; ++dx) {
                const float yy = y0 + (float)dy, xx = x0 + (float)dx;
                const float wb = (1.f - fabsf(py - yy)) * (1.f - fabsf(px - xx));
                const bool valid = (yy >= 0.f) && (yy < (float)HH) && (xx >= 0.f) && (xx < (float)WW);
                int yi = (int)yy; yi = yi < 0 ? 0 : (yi > HH - 1 ? HH - 1 : yi);
                int xi = (int)xx; xi = xi < 0 ? 0 : (xi > WW - 1 ? WW - 1 : xi);
                idxc[dy * 2 + dx] = yi * WW + xi;
                wgtc[dy * 2 + dx] = valid ? wb * m : 0.f;
            }
    };

    // pending early gathers for the NEXT chunk: its 0,1 (16 of this thread's 32 channels)
    ushort8 rgE0[4], rgE1[4];

    auto issueE = [&](int half) {
        const ushort* xb = xn + (size_t)b * HWSZ * CIN + half * 128 + sub * 32;
        #pragma unroll
        for (int cr = 0; cr < 4; ++cr)
            rgE0[cr] = *(const ushort8*)(xb + (size_t)idxc[cr] * CIN);
        #pragma unroll
        for (int cr = 0; cr < 4; ++cr)
            rgE1[cr] = *(const ushort8*)(xb + (size_t)idxc[cr] * CIN + 8);
    };

    // convert+write chunk c: uses rgE (issued last iteration); late half issued here,
    // its latency hidden under the early-half convert.
    auto convWrite = [&](int half, ushort* dstbuf) {
        const ushort* xb = xn + (size_t)b * HWSZ * CIN + half * 128 + sub * 32;
        ushort8 rgL0[4], rgL1[4];
        #pragma unroll
        for (int cr = 0; cr < 4; ++cr)
            rgL0[cr] = *(const ushort8*)(xb + (size_t)idxc[cr] * CIN + 16);
        #pragma unroll
        for (int cr = 0; cr < 4; ++cr)
            rgL1[cr] = *(const ushort8*)(xb + (size_t)idxc[cr] * CIN + 24);

        char* drow = (char*)dstbuf + pl * 256;
        const int sw = (pl & 15) << 4;
        ushort8 o;
        #pragma unroll
        for (int j = 0; j < 8; ++j)
            o[j] = f2bf(wgtc[0] * bf2f(rgE0[0][j]) + wgtc[1] * bf2f(rgE0[1][j])
                      + wgtc[2] * bf2f(rgE0[2][j]) + wgtc[3] * bf2f(rgE0[3][j]));
        *(ushort8*)(drow + ((sub * 64) ^ sw)) = o;
        #pragma unroll
        for (int j = 0; j < 8; ++j)
            o[j] = f2bf(wgtc[0] * bf2f(rgE1[0][j]) + wgtc[1] * bf2f(rgE1[1][j])
                      + wgtc[2] * bf2f(rgE1[2][j]) + wgtc[3] * bf2f(rgE1[3][j]));
        *(ushort8*)(drow + ((sub * 64 + 16) ^ sw)) = o;
        #pragma unroll
        for (int j = 0; j < 8; ++j)
            o[j] = f2bf(wgtc[0] * bf2f(rgL0[0][j]) + wgtc[1] * bf2f(rgL0[1][j])
                      + wgtc[2] * bf2f(rgL0[2][j]) + wgtc[3] * bf2f(rgL0[3][j]));
        *(ushort8*)(drow + ((sub * 64 + 32) ^ sw)) = o;
        #pragma unroll
        for (int j = 0; j < 8; ++j)
            o[j] = f2bf(wgtc[0] * bf2f(rgL1[0][j]) + wgtc[1] * bf2f(rgL1[1][j])
                      + wgtc[2] * bf2f(rgL1[2][j]) + wgtc[3] * bf2f(rgL1[3][j]));
        *(ushort8*)(drow + ((sub * 64 + 48) ^ sw)) = o;
    };

    f32x4 acc[4][4];
    #pragma unroll
    for (int i = 0; i < 4; ++i)
        #pragma unroll
        for (int j = 0; j < 4; ++j)
            acc[i][j] = (f32x4){0.f, 0.f, 0.f, 0.f};

    const int arow = lane & 15;
    const int akb  = lane >> 4;
    const int asw  = arow << 4;

    auto mfma_chunk = [&](int kb8base, const ushort* src) {
        const char* srow = (const char*)src;
        #pragma unroll
        for (int ks = 0; ks < 4; ++ks) {
            short8 af[4], bfr[4];
            const ushort* wrow = wp + ((size_t)(kb8base + ks * 4 + akb) * COUT + wid * 64 + arow) * 8;
            #pragma unroll
            for (int mt = 0; mt < 4; ++mt)
                af[mt] = *(const short8*)(wrow + mt * 16 * 8);
            const int cb = (ks * 64 + akb * 16) ^ asw;
            #pragma unroll
            for (int nt = 0; nt < 4; ++nt)
                bfr[nt] = *(const short8*)(srow + (arow + nt * 16) * 256 + cb);
            #pragma unroll
            for (int mt = 0; mt < 4; ++mt)
                #pragma unroll
                for (int nt = 0; nt < 4; ++nt)
                    acc[mt][nt] = __builtin_amdgcn_mfma_f32_16x16x32_bf16(
                        af[mt], bfr[nt], acc[mt][nt], 0, 0, 0);
        }
    };

    // pipeline: iter c = { convWrite(c); [coords; issueE(c+1)]; barrier; mfma(c) }
    coords(0);
    issueE(0);
    for (int c = 0; c < 18; ++c) {
        const int half = c & 1;
        convWrite(half, buf[half]);
        if (c < 17) {
            if (half == 1) coords((c + 1) >> 1);   // next chunk starts a new tap
            issueE((c + 1) & 1);                   // next-chunk early gathers in flight over mfma
        }
        __syncthreads();
        mfma_chunk(c * 16, buf[half]);
    }

    // ---- epilogue: C/D layout col=lane&15 (pos), row=(lane>>4)*4+r (cout)
    const int prow = lane & 15;
    const int crow = (lane >> 4) * 4;
    #pragma unroll
    for (int mt = 0; mt < 4; ++mt) {
        const int cout = wid * 64 + mt * 16 + crow;
        #pragma unroll
        for (int nt = 0; nt < 4; ++nt) {
            const int opos = p0 + nt * 16 + prow;
            float* op = out + ((size_t)b * COUT + cout) * HWSZ + opos;
            #pragma unroll
            for (int r = 0; r < 4; ++r)
                op[(size_t)r * HWSZ] = acc[mt][nt][r];
        }
    }

    // ---- GN partial stats: wave wid's mt-subtile is exactly group wid*4+mt
    #pragma unroll
    for (int mt = 0; mt < 4; ++mt) {
        float s = 0.f, q = 0.f;
        #pragma unroll
        for (int nt = 0; nt < 4; ++nt)
            #pragma unroll
            for (int r = 0; r < 4; ++r) {
                const float v = acc[mt][nt][r];
                s += v; q += v * v;
            }
        #pragma unroll
        for (int o = 32; o > 0; o >>= 1) {
            s += __shfl_xor(s, o);
            q += __shfl_xor(q, o);
        }
        if (lane == 0) {
            const int bg = b * GN_G + wid * 4 + mt;
            part[((size_t)bg * NPB + pblk) * 2]     = s;
            part[((size_t)bg * NPB + pblk) * 2 + 1] = q;
        }
    }
}

// ---- reduce partials -> stats[bg] = {mean, var}; 256 threads, 4 per bg
__global__ void gn_final_kernel(const float* __restrict__ part, float* __restrict__ stats) {
    const int t  = threadIdx.x;
    const int bg = t >> 2;
    const int j  = t & 3;
    float s = 0.f, q = 0.f;
    for (int i = j; i < NPB; i += 4) {
        s += part[((size_t)bg * NPB + i) * 2];
        q += part[((size_t)bg * NPB + i) * 2 + 1];
    }
    s += __shfl_xor(s, 1); q += __shfl_xor(q, 1);
    s += __shfl_xor(s, 2); q += __shfl_xor(q, 2);
    if (j == 0) {
        const float invn = 1.f / (float)((COUT / GN_G) * HWSZ);
        const float mean = s * invn;
        stats[bg * 2]     = mean;
        stats[bg * 2 + 1] = q * invn - mean * mean;
    }
}

// ---- GroupNorm apply (in place)
__global__ __launch_bounds__(256)
void gn_apply_kernel(float* __restrict__ y, const float* __restrict__ stats,
                     const float* __restrict__ gamma, const float* __restrict__ beta) {
    const int i = blockIdx.x * 256 + threadIdx.x;       // float4 index
    const int e = i * 4;
    const int c  = (e / HWSZ) & (COUT - 1);
    const int bg = e / (HWSZ * (COUT / GN_G));
    const float mean = stats[bg * 2];
    const float var  = stats[bg * 2 + 1];
    const float inv  = rsqrtf(var + EPSV);
    const float sc = inv * gamma[c];
    const float sh = beta[c] - mean * sc;
    float4 v = ((float4*)y)[i];
    v.x = v.x * sc + sh;
    v.y = v.y * sc + sh;
    v.z = v.z * sc + sh;
    v.w = v.w * sc + sh;
    ((float4*)y)[i] = v;
}

extern "C" void kernel_launch(void* const* d_in, const int* in_sizes, int n_in,
                              void* d_out, int out_size, void* d_ws, size_t ws_size,
                              hipStream_t stream) {
    const float* x      = (const float*)d_in[0];
    const float* offset = (const float*)d_in[1];
    const float* mask   = (const float*)d_in[2];
    const float* weight = (const float*)d_in[3];
    const float* gamma  = (const float*)d_in[4];
    const float* beta   = (const float*)d_in[5];
    float* out = (float*)d_out;

    // ws: xn bf16 (18.9 MB) | wp bf16 (1.18 MB) | part (73.8 KB) | stats (512 B)
    ushort* xn    = (ushort*)d_ws;
    ushort* wp    = xn + (size_t)BATCH * HWSZ * CIN;
    float*  part  = (float*)(wp + (size_t)9 * CIN * COUT);
    float*  stats = part + (size_t)BATCH * GN_G * NPB * 2;

    {
        dim3 g(HWSZ / 64, CIN / 64, BATCH);
        nhwc_kernel<<<g, 256, 0, stream>>>(x, xn);
    }
    repack_w_kernel<<<9 * CIN * COUT / 256, 256, 0, stream>>>(weight, wp);

    dcn_mfma_kernel<<<NWG, 256, 0, stream>>>(xn, offset, mask, wp, out, part);

    gn_final_kernel<<<1, 256, 0, stream>>>(part, stats);
    gn_apply_kernel<<<(size_t)BATCH * COUT * HWSZ / 4 / 256, 256, 0, stream>>>(out, stats, gamma, beta);
}

// Round 7
// 127.681 us; speedup vs baseline: 2.3623x; 1.5583x over previous
//
#include <hip/hip_runtime.h>
#include <cstdint>

typedef short  short8  __attribute__((ext_vector_type(8)));
typedef ushort ushort8 __attribute__((ext_vector_type(8)));
typedef float  f32x4   __attribute__((ext_vector_type(4)));

#define BATCH 4
#define CIN   256
#define COUT  256
#define HH    96
#define WW    96
#define HWSZ  9216
#define GN_G  16
#define EPSV  1e-5f
#define BN    64            // positions per block
#define NPB   144           // position-blocks per batch (9216/64)
#define NWG   (BATCH*NPB)   // 576 blocks, %8==0 -> bijective XCD swizzle

__device__ __forceinline__ float bf2f(ushort u) {
    return __uint_as_float(((uint32_t)u) << 16);
}
__device__ __forceinline__ ushort f2bf(float f) {
    uint32_t u = __float_as_uint(f);
    u += 0x7FFFu + ((u >> 16) & 1u);   // round-to-nearest-even
    return (ushort)(u >> 16);
}

// ---- x: [b][c][p] fp32 -> xn: [b][p][c] bf16 (tiled transpose via LDS)
__global__ __launch_bounds__(256)
void nhwc_kernel(const float* __restrict__ x, ushort* __restrict__ xn) {
    __shared__ ushort tile[64][66];
    const int b  = blockIdx.z;
    const int cb = blockIdx.y * 64;
    const int pb = blockIdx.x * 64;
    const int t  = threadIdx.x;
    {
        const int pl = t & 63;
        const int cq = t >> 6;
        #pragma unroll
        for (int i = 0; i < 16; ++i) {
            const int c = cq * 16 + i;
            tile[c][pl] = f2bf(x[((size_t)b * CIN + cb + c) * HWSZ + pb + pl]);
        }
    }
    __syncthreads();
    {
        const int cl = t & 63;
        const int pq = t >> 6;
        #pragma unroll
        for (int i = 0; i < 16; ++i) {
            const int p = pq * 16 + i;
            xn[((size_t)b * HWSZ + pb + p) * CIN + cb + cl] = tile[cl][p];
        }
    }
}

// ---- weight [cout][cin][3][3] fp32 -> Wp[kb8][cout][8] bf16, globalK = tap*256 + cin
__global__ __launch_bounds__(256)
void repack_w_kernel(const float* __restrict__ w, ushort* __restrict__ wp) {
    const int d    = blockIdx.x * 256 + threadIdx.x;
    const int j    = d & 7;
    const int cout = (d >> 3) & 255;
    const int kb8  = d >> 11;
    const int ktap = kb8 >> 5;
    const int cin  = ((kb8 & 31) << 3) | j;
    wp[d] = f2bf(w[cout * (CIN * 9) + cin * 9 + ktap]);
}

// ---- fused deformable-conv GEMM + GN partial stats (coalesced gathers)
__global__ __launch_bounds__(256, 3)
void dcn_mfma_kernel(const ushort* __restrict__ xn, const float* __restrict__ off,
                     const float* __restrict__ msk, const ushort* __restrict__ wp,
                     float* __restrict__ out, float* __restrict__ part) {
    __shared__ ushort buf[2][BN * 128];   // 2 x 16 KB, swizzled 256B rows
    __shared__ int    s_idx[2][BN][4];    // per-tap coords, double-buffered by tap&1
    __shared__ float  s_wgt[2][BN][4];

    const int bid  = blockIdx.x;
    const int swz  = (bid & 7) * (NWG / 8) + (bid >> 3);   // XCD-contiguous chunks
    const int b    = swz / NPB;
    const int pblk = swz - b * NPB;
    const int p0   = pblk * BN;

    const int t    = threadIdx.x;
    const int lane = t & 63;
    const int wid  = t >> 6;

    // ---- coords for one tap, computed by t<64 (one thread per position)
    auto coords = [&](int k) {
        if (t < BN) {
            const int slot = k & 1;
            const int pos  = p0 + t;
            const int hh   = pos / WW;
            const int ww   = pos - hh * WW;
            const size_t obase = ((size_t)b * 18 + 2 * k) * HWSZ + pos;
            const float oy = off[obase];
            const float ox = off[obase + HWSZ];
            const float m  = msk[((size_t)b * 9 + k) * HWSZ + pos];
            const float py = (float)(hh + k / 3 - 1) + oy;
            const float px = (float)(ww + k % 3 - 1) + ox;
            const float y0 = floorf(py), x0 = floorf(px);
            #pragma unroll
            for (int dy = 0; dy < 2; ++dy)
                #pragma unroll
                for (int dx = 0; dx < 2; ++dx) {
                    const float yy = y0 + (float)dy, xx = x0 + (float)dx;
                    const float wb = (1.f - fabsf(py - yy)) * (1.f - fabsf(px - xx));
                    const bool valid = (yy >= 0.f) && (yy < (float)HH) && (xx >= 0.f) && (xx < (float)WW);
                    int yi = (int)yy; yi = yi < 0 ? 0 : (yi > HH - 1 ? HH - 1 : yi);
                    int xi = (int)xx; xi = xi < 0 ? 0 : (xi > WW - 1 ? WW - 1 : xi);
                    s_idx[slot][t][dy * 2 + dx] = yi * WW + xi;
                    s_wgt[slot][t][dy * 2 + dx] = valid ? wb * m : 0.f;
                }
        }
    };

    // ---- stage chunk c (half-tap, 128 ch): wave wid owns positions [wid*16, wid*16+16)
    // 16-lane group per (position): lane = sp*16 + c16; each gather instruction is
    // 4 positions x 256B contiguous = 8 cache lines, zero redundancy.
    const int sp  = lane >> 4;
    const int c16 = lane & 15;
    auto stage = [&](int c, ushort* dstbuf) {
        const int tap  = c >> 1;
        const int half = c & 1;
        const int slot = tap & 1;
        const ushort* xb = xn + (size_t)b * HWSZ * CIN + half * 128 + c16 * 8;
        #pragma unroll
        for (int g = 0; g < 4; ++g) {
            const int p = wid * 16 + g * 4 + sp;
            float vacc[8];
            #pragma unroll
            for (int j = 0; j < 8; ++j) vacc[j] = 0.f;
            #pragma unroll
            for (int cr = 0; cr < 4; ++cr) {
                const int   ix = s_idx[slot][p][cr];
                const float w  = s_wgt[slot][p][cr];
                const ushort8 v = *(const ushort8*)(xb + (size_t)ix * CIN);
                #pragma unroll
                for (int j = 0; j < 8; ++j)
                    vacc[j] += w * bf2f(v[j]);
            }
            ushort8 o;
            #pragma unroll
            for (int j = 0; j < 8; ++j) o[j] = f2bf(vacc[j]);
            char* drow = (char*)dstbuf + p * 256;
            *(ushort8*)(drow + ((c16 * 16) ^ ((p & 15) << 4))) = o;
        }
    };

    f32x4 acc[4][4];
    #pragma unroll
    for (int i = 0; i < 4; ++i)
        #pragma unroll
        for (int j = 0; j < 4; ++j)
            acc[i][j] = (f32x4){0.f, 0.f, 0.f, 0.f};

    const int arow = lane & 15;
    const int akb  = lane >> 4;
    const int asw  = arow << 4;

    // A loads for one ks-step of chunk c
    auto loadA = [&](int kb8base, int ks, short8 af[4]) {
        const ushort* wrow = wp + ((size_t)(kb8base + ks * 4 + akb) * COUT + wid * 64 + arow) * 8;
        #pragma unroll
        for (int mt = 0; mt < 4; ++mt)
            af[mt] = *(const short8*)(wrow + mt * 16 * 8);
    };

    // MFMA over one chunk (128 ch = 4 ks-steps), 2-stage A pipeline; afA preloaded.
    auto mfma_chunk = [&](int kb8base, const ushort* src, short8 afA[4]) {
        const char* srow = (const char*)src;
        short8 afB[4];
        #pragma unroll
        for (int ks = 0; ks < 4; ++ks) {
            if (ks < 3) loadA(kb8base, ks + 1, (ks & 1) ? afA : afB);
            short8* afc = (ks & 1) ? afB : afA;
            short8 bfr[4];
            const int cb = (ks * 64 + akb * 16) ^ asw;
            #pragma unroll
            for (int nt = 0; nt < 4; ++nt)
                bfr[nt] = *(const short8*)(srow + (arow + nt * 16) * 256 + cb);
            #pragma unroll
            for (int mt = 0; mt < 4; ++mt)
                #pragma unroll
                for (int nt = 0; nt < 4; ++nt)
                    acc[mt][nt] = __builtin_amdgcn_mfma_f32_16x16x32_bf16(
                        afc[mt], bfr[nt], acc[mt][nt], 0, 0, 0);
        }
    };

    // ---- pipeline: 1 barrier per chunk; coords(tap+1) computed during even chunks
    coords(0);
    __syncthreads();
    stage(0, buf[0]);
    for (int c = 0; c < 18; ++c) {
        if (c < 17) stage(c + 1, buf[(c + 1) & 1]);
        if (!(c & 1) && (c >> 1) + 1 < 9) coords((c >> 1) + 1);
        short8 afA[4];
        loadA(c * 16, 0, afA);            // first-A preload, no LDS dependency
        __syncthreads();
        mfma_chunk(c * 16, buf[c & 1], afA);
    }

    // ---- epilogue: C/D layout col=lane&15 (pos), row=(lane>>4)*4+r (cout)
    const int prow = lane & 15;
    const int crow = (lane >> 4) * 4;
    #pragma unroll
    for (int mt = 0; mt < 4; ++mt) {
        const int cout = wid * 64 + mt * 16 + crow;
        #pragma unroll
        for (int nt = 0; nt < 4; ++nt) {
            const int opos = p0 + nt * 16 + prow;
            float* op = out + ((size_t)b * COUT + cout) * HWSZ + opos;
            #pragma unroll
            for (int r = 0; r < 4; ++r)
                op[(size_t)r * HWSZ] = acc[mt][nt][r];
        }
    }

    // ---- GN partial stats: wave wid's mt-subtile is exactly group wid*4+mt
    #pragma unroll
    for (int mt = 0; mt < 4; ++mt) {
        float s = 0.f, q = 0.f;
        #pragma unroll
        for (int nt = 0; nt < 4; ++nt)
            #pragma unroll
            for (int r = 0; r < 4; ++r) {
                const float v = acc[mt][nt][r];
                s += v; q += v * v;
            }
        #pragma unroll
        for (int o = 32; o > 0; o >>= 1) {
            s += __shfl_xor(s, o);
            q += __shfl_xor(q, o);
        }
        if (lane == 0) {
            const int bg = b * GN_G + wid * 4 + mt;
            part[((size_t)bg * NPB + pblk) * 2]     = s;
            part[((size_t)bg * NPB + pblk) * 2 + 1] = q;
        }
    }
}

// ---- reduce partials -> stats[bg] = {mean, var}; 256 threads, 4 per bg
__global__ void gn_final_kernel(const float* __restrict__ part, float* __restrict__ stats) {
    const int t  = threadIdx.x;
    const int bg = t >> 2;
    const int j  = t & 3;
    float s = 0.f, q = 0.f;
    for (int i = j; i < NPB; i += 4) {
        s += part[((size_t)bg * NPB + i) * 2];
        q += part[((size_t)bg * NPB + i) * 2 + 1];
    }
    s += __shfl_xor(s, 1); q += __shfl_xor(q, 1);
    s += __shfl_xor(s, 2); q += __shfl_xor(q, 2);
    if (j == 0) {
        const float invn = 1.f / (float)((COUT / GN_G) * HWSZ);
        const float mean = s * invn;
        stats[bg * 2]     = mean;
        stats[bg * 2 + 1] = q * invn - mean * mean;
    }
}

// ---- GroupNorm apply (in place)
__global__ __launch_bounds__(256)
void gn_apply_kernel(float* __restrict__ y, const float* __restrict__ stats,
                     const float* __restrict__ gamma, const float* __restrict__ beta) {
    const int i = blockIdx.x * 256 + threadIdx.x;       // float4 index
    const int e = i * 4;
    const int c  = (e / HWSZ) & (COUT - 1);
    const int bg = e / (HWSZ * (COUT / GN_G));
    const float mean = stats[bg * 2];
    const float var  = stats[bg * 2 + 1];
    const float inv  = rsqrtf(var + EPSV);
    const float sc = inv * gamma[c];
    const float sh = beta[c] - mean * sc;
    float4 v = ((float4*)y)[i];
    v.x = v.x * sc + sh;
    v.y = v.y * sc + sh;
    v.z = v.z * sc + sh;
    v.w = v.w * sc + sh;
    ((float4*)y)[i] = v;
}

extern "C" void kernel_launch(void* const* d_in, const int* in_sizes, int n_in,
                              void* d_out, int out_size, void* d_ws, size_t ws_size,
                              hipStream_t stream) {
    const float* x      = (const float*)d_in[0];
    const float* offset = (const float*)d_in[1];
    const float* mask   = (const float*)d_in[2];
    const float* weight = (const float*)d_in[3];
    const float* gamma  = (const float*)d_in[4];
    const float* beta   = (const float*)d_in[5];
    float* out = (float*)d_out;

    // ws: xn bf16 (18.9 MB) | wp bf16 (1.18 MB) | part (73.8 KB) | stats (512 B)
    ushort* xn    = (ushort*)d_ws;
    ushort* wp    = xn + (size_t)BATCH * HWSZ * CIN;
    float*  part  = (float*)(wp + (size_t)9 * CIN * COUT);
    float*  stats = part + (size_t)BATCH * GN_G * NPB * 2;

    {
        dim3 g(HWSZ / 64, CIN / 64, BATCH);
        nhwc_kernel<<<g, 256, 0, stream>>>(x, xn);
    }
    repack_w_kernel<<<9 * CIN * COUT / 256, 256, 0, stream>>>(weight, wp);

    dcn_mfma_kernel<<<NWG, 256, 0, stream>>>(xn, offset, mask, wp, out, part);

    gn_final_kernel<<<1, 256, 0, stream>>>(part, stats);
    gn_apply_kernel<<<(size_t)BATCH * COUT * HWSZ / 4 / 256, 256, 0, stream>>>(out, stats, gamma, beta);
}

// Round 8
// 126.284 us; speedup vs baseline: 2.3885x; 1.0111x over previous
//
#include <hip/hip_runtime.h>
#include <hip/hip_bf16.h>
#include <cstdint>

typedef short  short8  __attribute__((ext_vector_type(8)));
typedef ushort ushort8 __attribute__((ext_vector_type(8)));
typedef float  f32x4   __attribute__((ext_vector_type(4)));

#define BATCH 4
#define CIN   256
#define COUT  256
#define HH    96
#define WW    96
#define HWSZ  9216
#define GN_G  16
#define EPSV  1e-5f
#define BN    64            // positions per block
#define NPB   144           // position-blocks per batch (9216/64)
#define NWG   (BATCH*NPB)   // 576 blocks, %8==0 -> bijective XCD swizzle

__device__ __forceinline__ float bf2f(ushort u) {
    return __uint_as_float(((uint32_t)u) << 16);
}
__device__ __forceinline__ ushort f2bf(float f) {
    uint32_t u = __float_as_uint(f);
    u += 0x7FFFu + ((u >> 16) & 1u);   // round-to-nearest-even
    return (ushort)(u >> 16);
}

// ---- x: [b][c][p] fp32 -> xn: [b][p][c] bf16 (tiled transpose via LDS)
__global__ __launch_bounds__(256)
void nhwc_kernel(const float* __restrict__ x, ushort* __restrict__ xn) {
    __shared__ ushort tile[64][66];
    const int b  = blockIdx.z;
    const int cb = blockIdx.y * 64;
    const int pb = blockIdx.x * 64;
    const int t  = threadIdx.x;
    {
        const int pl = t & 63;
        const int cq = t >> 6;
        #pragma unroll
        for (int i = 0; i < 16; ++i) {
            const int c = cq * 16 + i;
            tile[c][pl] = f2bf(x[((size_t)b * CIN + cb + c) * HWSZ + pb + pl]);
        }
    }
    __syncthreads();
    {
        const int cl = t & 63;
        const int pq = t >> 6;
        #pragma unroll
        for (int i = 0; i < 16; ++i) {
            const int p = pq * 16 + i;
            xn[((size_t)b * HWSZ + pb + p) * CIN + cb + cl] = tile[cl][p];
        }
    }
}

// ---- weight [cout][cin][3][3] fp32 -> Wp[kb8][cout][8] bf16, globalK = tap*256 + cin
__global__ __launch_bounds__(256)
void repack_w_kernel(const float* __restrict__ w, ushort* __restrict__ wp) {
    const int d    = blockIdx.x * 256 + threadIdx.x;
    const int j    = d & 7;
    const int cout = (d >> 3) & 255;
    const int kb8  = d >> 11;
    const int ktap = kb8 >> 5;
    const int cin  = ((kb8 & 31) << 3) | j;
    wp[d] = f2bf(w[cout * (CIN * 9) + cin * 9 + ktap]);
}

// ---- fused deformable-conv GEMM + GN partial stats (full T14 async-stage)
__global__ __launch_bounds__(256, 3)
void dcn_mfma_kernel(const ushort* __restrict__ xn, const float* __restrict__ off,
                     const float* __restrict__ msk, const ushort* __restrict__ wp,
                     float* __restrict__ out, float* __restrict__ part) {
    __shared__ ushort buf[2][BN * 128];   // 2 x 16 KB, swizzled 256B rows
    __shared__ int    s_idx[2][BN][4];    // per-tap coords, slot = tap&1
    __shared__ float  s_wgt[2][BN][4];

    const int bid  = blockIdx.x;
    const int swz  = (bid & 7) * (NWG / 8) + (bid >> 3);   // XCD-contiguous chunks
    const int b    = swz / NPB;
    const int pblk = swz - b * NPB;
    const int p0   = pblk * BN;

    const int t    = threadIdx.x;
    const int lane = t & 63;
    const int wid  = t >> 6;

    // ---- coords for one tap, computed by t<64 (one thread per position)
    auto coords = [&](int k) {
        if (t < BN) {
            const int slot = k & 1;
            const int pos  = p0 + t;
            const int hh   = pos / WW;
            const int ww   = pos - hh * WW;
            const size_t obase = ((size_t)b * 18 + 2 * k) * HWSZ + pos;
            const float oy = off[obase];
            const float ox = off[obase + HWSZ];
            const float m  = msk[((size_t)b * 9 + k) * HWSZ + pos];
            const float py = (float)(hh + k / 3 - 1) + oy;
            const float px = (float)(ww + k % 3 - 1) + ox;
            const float y0 = floorf(py), x0 = floorf(px);
            #pragma unroll
            for (int dy = 0; dy < 2; ++dy)
                #pragma unroll
                for (int dx = 0; dx < 2; ++dx) {
                    const float yy = y0 + (float)dy, xx = x0 + (float)dx;
                    const float wb = (1.f - fabsf(py - yy)) * (1.f - fabsf(px - xx));
                    const bool valid = (yy >= 0.f) && (yy < (float)HH) && (xx >= 0.f) && (xx < (float)WW);
                    int yi = (int)yy; yi = yi < 0 ? 0 : (yi > HH - 1 ? HH - 1 : yi);
                    int xi = (int)xx; xi = xi < 0 ? 0 : (xi > WW - 1 ? WW - 1 : xi);
                    s_idx[slot][t][dy * 2 + dx] = yi * WW + xi;
                    s_wgt[slot][t][dy * 2 + dx] = valid ? wb * m : 0.f;
                }
        }
    };

    // 16-lane group per position: lane = sp*16 + c16; 4 positions per gather inst,
    // 256B contiguous per (position,corner) -> zero line redundancy.
    const int sp  = lane >> 4;
    const int c16 = lane & 15;

    // early gathers (groups 0,1) held in regs across the MFMA phase
    ushort8 rgE[2][4];

    auto issueG = [&](int c) {
        const int tap = c >> 1, half = c & 1, slot = tap & 1;
        const ushort* xb = xn + (size_t)b * HWSZ * CIN + half * 128 + c16 * 8;
        #pragma unroll
        for (int g = 0; g < 2; ++g) {
            const int p = wid * 16 + g * 4 + sp;
            #pragma unroll
            for (int cr = 0; cr < 4; ++cr)
                rgE[g][cr] = *(const ushort8*)(xb + (size_t)s_idx[slot][p][cr] * CIN);
        }
    };

    // late gathers (groups 2,3) issued here, covered by groups 0,1's combine (L2-hit)
    auto convWrite = [&](int c, ushort* dstbuf) {
        const int tap = c >> 1, half = c & 1, slot = tap & 1;
        const ushort* xb = xn + (size_t)b * HWSZ * CIN + half * 128 + c16 * 8;
        ushort8 rgL[2][4];
        #pragma unroll
        for (int g = 0; g < 2; ++g) {
            const int p = wid * 16 + (g + 2) * 4 + sp;
            #pragma unroll
            for (int cr = 0; cr < 4; ++cr)
                rgL[g][cr] = *(const ushort8*)(xb + (size_t)s_idx[slot][p][cr] * CIN);
        }
        #pragma unroll
        for (int g = 0; g < 4; ++g) {
            const int p = wid * 16 + g * 4 + sp;
            const ushort8* rgp = (g < 2) ? rgE[g] : rgL[g - 2];
            float vacc[8] = {0.f, 0.f, 0.f, 0.f, 0.f, 0.f, 0.f, 0.f};
            #pragma unroll
            for (int cr = 0; cr < 4; ++cr) {
                const float w  = s_wgt[slot][p][cr];
                const ushort8 v = rgp[cr];
                #pragma unroll
                for (int j = 0; j < 8; ++j)
                    vacc[j] += w * bf2f(v[j]);
            }
            ushort8 o;
            #pragma unroll
            for (int j = 0; j < 8; j += 2) {      // pair casts -> v_cvt_pk_bf16_f32
                const __hip_bfloat162 h2 = __float22bfloat162_rn(float2{vacc[j], vacc[j + 1]});
                const uint32_t u = *reinterpret_cast<const uint32_t*>(&h2);
                o[j]     = (ushort)u;
                o[j + 1] = (ushort)(u >> 16);
            }
            char* drow = (char*)dstbuf + p * 256;
            *(ushort8*)(drow + ((c16 * 16) ^ ((p & 15) << 4))) = o;
        }
    };

    f32x4 acc[4][4];
    #pragma unroll
    for (int i = 0; i < 4; ++i)
        #pragma unroll
        for (int j = 0; j < 4; ++j)
            acc[i][j] = (f32x4){0.f, 0.f, 0.f, 0.f};

    const int arow = lane & 15;
    const int akb  = lane >> 4;
    const int asw  = arow << 4;

    auto loadA = [&](int kb8base, int ks, short8 af[4]) {
        const ushort* wrow = wp + ((size_t)(kb8base + ks * 4 + akb) * COUT + wid * 64 + arow) * 8;
        #pragma unroll
        for (int mt = 0; mt < 4; ++mt)
            af[mt] = *(const short8*)(wrow + mt * 16 * 8);
    };

    auto mfma_chunk = [&](int kb8base, const ushort* src, short8 afA[4]) {
        const char* srow = (const char*)src;
        short8 afB[4];
        #pragma unroll
        for (int ks = 0; ks < 4; ++ks) {
            if (ks < 3) loadA(kb8base, ks + 1, (ks & 1) ? afA : afB);
            short8* afc = (ks & 1) ? afB : afA;
            short8 bfr[4];
            const int cb = (ks * 64 + akb * 16) ^ asw;
            #pragma unroll
            for (int nt = 0; nt < 4; ++nt)
                bfr[nt] = *(const short8*)(srow + (arow + nt * 16) * 256 + cb);
            #pragma unroll
            for (int mt = 0; mt < 4; ++mt)
                #pragma unroll
                for (int nt = 0; nt < 4; ++nt)
                    acc[mt][nt] = __builtin_amdgcn_mfma_f32_16x16x32_bf16(
                        afc[mt], bfr[nt], acc[mt][nt], 0, 0, 0);
        }
    };

    // ---- pipeline (1 barrier/chunk):
    //   iter c: issueG(c+1) | mfma(c) | convWrite(c+1) | [odd c: coords(c/2+2)] | barrier
    // slot safety: iter 2t+1 readers use tap t+1 (slot (t+1)&1); coords(t+2) writes
    // slot t&1 -> disjoint. tap t+2 first read at iter 2t+3, published at barrier 2t+1.
    coords(0);
    __syncthreads();
    issueG(0);
    convWrite(0, buf[0]);     // prologue: uncovered wait, once
    coords(1);
    __syncthreads();
    for (int c = 0; c < 18; ++c) {
        if (c < 17) {
            issueG(c + 1);
            __builtin_amdgcn_sched_barrier(0);   // pin gather issue before MFMA phase
        }
        short8 afA[4];
        loadA(c * 16, 0, afA);
        mfma_chunk(c * 16, buf[c & 1], afA);
        if (c < 17) convWrite(c + 1, buf[(c + 1) & 1]);
        if ((c & 1) && ((c >> 1) + 2 <= 8)) coords((c >> 1) + 2);
        __syncthreads();
    }

    // ---- epilogue: C/D layout col=lane&15 (pos), row=(lane>>4)*4+r (cout)
    const int prow = lane & 15;
    const int crow = (lane >> 4) * 4;
    #pragma unroll
    for (int mt = 0; mt < 4; ++mt) {
        const int cout = wid * 64 + mt * 16 + crow;
        #pragma unroll
        for (int nt = 0; nt < 4; ++nt) {
            const int opos = p0 + nt * 16 + prow;
            float* op = out + ((size_t)b * COUT + cout) * HWSZ + opos;
            #pragma unroll
            for (int r = 0; r < 4; ++r)
                op[(size_t)r * HWSZ] = acc[mt][nt][r];
        }
    }

    // ---- GN partial stats: wave wid's mt-subtile is exactly group wid*4+mt
    #pragma unroll
    for (int mt = 0; mt < 4; ++mt) {
        float s = 0.f, q = 0.f;
        #pragma unroll
        for (int nt = 0; nt < 4; ++nt)
            #pragma unroll
            for (int r = 0; r < 4; ++r) {
                const float v = acc[mt][nt][r];
                s += v; q += v * v;
            }
        #pragma unroll
        for (int o = 32; o > 0; o >>= 1) {
            s += __shfl_xor(s, o);
            q += __shfl_xor(q, o);
        }
        if (lane == 0) {
            const int bg = b * GN_G + wid * 4 + mt;
            part[((size_t)bg * NPB + pblk) * 2]     = s;
            part[((size_t)bg * NPB + pblk) * 2 + 1] = q;
        }
    }
}

// ---- reduce partials -> stats[bg] = {mean, var}; 256 threads, 4 per bg
__global__ void gn_final_kernel(const float* __restrict__ part, float* __restrict__ stats) {
    const int t  = threadIdx.x;
    const int bg = t >> 2;
    const int j  = t & 3;
    float s = 0.f, q = 0.f;
    for (int i = j; i < NPB; i += 4) {
        s += part[((size_t)bg * NPB + i) * 2];
        q += part[((size_t)bg * NPB + i) * 2 + 1];
    }
    s += __shfl_xor(s, 1); q += __shfl_xor(q, 1);
    s += __shfl_xor(s, 2); q += __shfl_xor(q, 2);
    if (j == 0) {
        const float invn = 1.f / (float)((COUT / GN_G) * HWSZ);
        const float mean = s * invn;
        stats[bg * 2]     = mean;
        stats[bg * 2 + 1] = q * invn - mean * mean;
    }
}

// ---- GroupNorm apply (in place)
__global__ __launch_bounds__(256)
void gn_apply_kernel(float* __restrict__ y, const float* __restrict__ stats,
                     const float* __restrict__ gamma, const float* __restrict__ beta) {
    const int i = blockIdx.x * 256 + threadIdx.x;       // float4 index
    const int e = i * 4;
    const int c  = (e / HWSZ) & (COUT - 1);
    const int bg = e / (HWSZ * (COUT / GN_G));
    const float mean = stats[bg * 2];
    const float var  = stats[bg * 2 + 1];
    const float inv  = rsqrtf(var + EPSV);
    const float sc = inv * gamma[c];
    const float sh = beta[c] - mean * sc;
    float4 v = ((float4*)y)[i];
    v.x = v.x * sc + sh;
    v.y = v.y * sc + sh;
    v.z = v.z * sc + sh;
    v.w = v.w * sc + sh;
    ((float4*)y)[i] = v;
}

extern "C" void kernel_launch(void* const* d_in, const int* in_sizes, int n_in,
                              void* d_out, int out_size, void* d_ws, size_t ws_size,
                              hipStream_t stream) {
    const float* x      = (const float*)d_in[0];
    const float* offset = (const float*)d_in[1];
    const float* mask   = (const float*)d_in[2];
    const float* weight = (const float*)d_in[3];
    const float* gamma  = (const float*)d_in[4];
    const float* beta   = (const float*)d_in[5];
    float* out = (float*)d_out;

    // ws: xn bf16 (18.9 MB) | wp bf16 (1.18 MB) | part (73.8 KB) | stats (512 B)
    ushort* xn    = (ushort*)d_ws;
    ushort* wp    = xn + (size_t)BATCH * HWSZ * CIN;
    float*  part  = (float*)(wp + (size_t)9 * CIN * COUT);
    float*  stats = part + (size_t)BATCH * GN_G * NPB * 2;

    {
        dim3 g(HWSZ / 64, CIN / 64, BATCH);
        nhwc_kernel<<<g, 256, 0, stream>>>(x, xn);
    }
    repack_w_kernel<<<9 * CIN * COUT / 256, 256, 0, stream>>>(weight, wp);

    dcn_mfma_kernel<<<NWG, 256, 0, stream>>>(xn, offset, mask, wp, out, part);

    gn_final_kernel<<<1, 256, 0, stream>>>(part, stats);
    gn_apply_kernel<<<(size_t)BATCH * COUT * HWSZ / 4 / 256, 256, 0, stream>>>(out, stats, gamma, beta);
}